// Round 14
// baseline (714.139 us; speedup 1.0000x reference)
//
#include <hip/hip_runtime.h>
#include <cstdint>
#include <cmath>

#define B_    64
#define K_    4096
#define DIM_  50257
#define DIMP_ 50688          // 198*256, zero-padded log table (round-2 value)
#define KNN_  8
#define NSEG_ 4
#define SEGD_ 12800          // segs 0-2: 25 superblocks; seg 3: 24 (guarded tail)
#define SB_   512
#define LN2_  0.6931471805599453

typedef float f32x4 __attribute__((ext_vector_type(4)));
typedef float f32x2 __attribute__((ext_vector_type(2)));

// ---------- kernel A: LT[b][d] = log2(logits[b][d]), zero-padded (r2-exact) --
__global__ void log_kernel(const float* __restrict__ logits, float* __restrict__ LT) {
    int d = blockIdx.x * 256 + threadIdx.x;     // 0..DIMP_-1
    int b = blockIdx.y;
    float v = 0.0f;
    if (d < DIM_) v = __log2f(logits[(size_t)b * DIM_ + d]);
    LT[(size_t)b * DIMP_ + d] = v;
}

// ---------- kernel B: big pass — r12 math chains VERBATIM, but BARRIER-FREE:
// av quads load directly from global A (same f32 values as the LDS-staged
// copies -> bit-exact), so ds_write/ds_read/per-sb __syncthreads all go away.
// The 4 waves decouple; L1 dedups their shared av lines. t1 keeps its own 16
// scalar loads in the r2 (srow, sl2, j-ascending) pattern. Straddling sb
// (seg 3 last) uses element-guarded av: pad 1.0 x Lv 0 = exact no-op, the
// same values r12 staged. One barrier remains (t1 epilogue gather).
__global__ __attribute__((amdgpu_flat_work_group_size(256, 256), amdgpu_waves_per_eu(2, 4)))
void main_kernel(
        const float* __restrict__ A, const float* __restrict__ LT,
        float* __restrict__ Spart, float* __restrict__ t1part) {
    __shared__ float T1L[8][64];         // 2 KB (t1 epilogue only)

    const int t    = threadIdx.x;        // 0..255
    const int lane = t & 63;
    const int wv   = t >> 6;             // 0..3

    const int bid  = blockIdx.x;         // 0..4095
    const int xcd  = bid & 7;
    const int seg  = xcd >> 1;           // 0..3 (XCD-pinned L slice)
    const int h    = xcd & 1;            // b-half
    const int kt8  = bid >> 3;           // 0..511
    const int kbase = kt8 * 8;

    const int d0   = seg * SEGD_;
    const int dend = min(d0 + SEGD_, DIM_);

    const int srow = t >> 5;             // t1 row 0..7
    const int sl2  = t & 31;             // t1 col base (covers sl2 and sl2+32)
    const float* Arow_t1 = A + (size_t)(kbase + srow) * DIM_;
    const float* LTb0    = LT + (size_t)(h * 32 + wv * 8) * DIMP_;
    const float* Ar0     = A + (size_t)kbase * DIM_;   // row r at Ar0 + r*DIM_

    f32x2 acc2[8][4];                    // [cc][p] packs acc[cc][2p], acc[cc][2p+1]
#pragma unroll
    for (int cc = 0; cc < 8; ++cc)
#pragma unroll
        for (int p = 0; p < 4; ++p) { acc2[cc][p][0] = 0.0f; acc2[cc][p][1] = 0.0f; }
    float t1a = 0.0f, t1b = 0.0f;        // chains for (srow, sl2), (srow, sl2+32)

    for (int ds = d0; ds < dend; ds += SB_) {
        const bool full = (ds + SB_ <= DIM_);   // block-uniform

        // ---- t1: batch 16 loads (r2 pattern), then chains (j asc, a1 then a2)
        float a1[8], a2[8];
        if (full) {
#pragma unroll
            for (int j = 0; j < 8; ++j) {
                a1[j] = Arow_t1[ds + sl2 + j * 64];
                a2[j] = Arow_t1[ds + sl2 + 32 + j * 64];
            }
        } else {
#pragma unroll
            for (int j = 0; j < 8; ++j) {
                const int dA = ds + sl2 + j * 64;
                a1[j] = (dA < DIM_) ? Arow_t1[dA] : 1.0f;   // pad 1.0: t1 += 0
                const int dB = dA + 32;
                a2[j] = (dB < DIM_) ? Arow_t1[dB] : 1.0f;
            }
        }
#pragma unroll
        for (int j = 0; j < 8; ++j) {
            t1a = fmaf(a1[j], __log2f(a1[j]), t1a);
            t1b = fmaf(a2[j], __log2f(a2[j]), t1b);
        }

        // ---- FMA phase: r12 packed micro-kernel, av from GLOBAL (bit-equal)
#pragma unroll
        for (int slot = 0; slot < 2; ++slot) {
            const int dl = slot * 256 + lane * 4;
            const float* LTd = LTb0 + ds + dl;
            f32x4 Lv[8];
#pragma unroll
            for (int cc = 0; cc < 8; ++cc)
                __builtin_memcpy(&Lv[cc], LTd + (size_t)cc * DIMP_, 16);
            f32x4 av[8];
            if (full) {
#pragma unroll
                for (int r = 0; r < 8; ++r)
                    __builtin_memcpy(&av[r], Ar0 + (size_t)r * DIM_ + ds + dl, 16);
            } else {
#pragma unroll
                for (int r = 0; r < 8; ++r) {
#pragma unroll
                    for (int q = 0; q < 4; ++q) {
                        const int d = ds + dl + q;
                        av[r][q] = (d < DIM_) ? Ar0[(size_t)r * DIM_ + d] : 1.0f;
                    }   // d>=DIM_: 1.0 * Lv(=0) -> acc unchanged, exactly r12
                }
            }

            f32x2 avp[4][4];             // [comp][p] = (av[2p].comp, av[2p+1].comp)
#pragma unroll
            for (int p = 0; p < 4; ++p) {
#pragma unroll
                for (int comp = 0; comp < 4; ++comp) {
                    avp[comp][p][0] = av[2 * p][comp];
                    avp[comp][p][1] = av[2 * p + 1][comp];
                }
            }
#pragma unroll
            for (int cc = 0; cc < 8; ++cc) {
#pragma unroll
                for (int comp = 0; comp < 4; ++comp) {
                    f32x2 bb;
                    bb[0] = Lv[cc][comp];
                    bb[1] = Lv[cc][comp];
#pragma unroll
                    for (int p = 0; p < 4; ++p)
                        acc2[cc][p] = __builtin_elementwise_fma(avp[comp][p], bb, acc2[cc][p]);
                }
            }
        }
    }

    // ---- epilogue: r2-exact xor-tree (32..1); lane cc*8+r keeps its element
    float outv = 0.0f;
#pragma unroll
    for (int cc = 0; cc < 8; ++cc)
#pragma unroll
        for (int r = 0; r < 8; ++r) {
            float v = (r & 1) ? acc2[cc][r >> 1][1] : acc2[cc][r >> 1][0];
            v += __shfl_xor(v, 32, 64);
            v += __shfl_xor(v, 16, 64);
            v += __shfl_xor(v, 8, 64);
            v += __shfl_xor(v, 4, 64);
            v += __shfl_xor(v, 2, 64);
            v += __shfl_xor(v, 1, 64);
            if (lane == cc * 8 + r) outv = v;
        }
    {
        const int rr  = lane & 7;        // k-row within tile
        const int ccx = lane >> 3;       // b within wave's 8-col group
        Spart[((size_t)(kbase + rr) * 64 + (h * 4 + wv) * 8 + ccx) * NSEG_ + seg] = outv;
    }

    // ---- t1: gather chains to LDS, wave 0 runs the r2-exact xor-tree per row
    T1L[srow][sl2]      = t1a;
    T1L[srow][sl2 + 32] = t1b;
    __syncthreads();                     // the ONLY barrier in the kernel
    if (wv == 0) {
#pragma unroll
        for (int row = 0; row < 8; ++row) {
            float s = T1L[row][lane];
            s += __shfl_xor(s, 32, 64);
            s += __shfl_xor(s, 16, 64);
            s += __shfl_xor(s, 8, 64);
            s += __shfl_xor(s, 4, 64);
            s += __shfl_xor(s, 2, 64);
            s += __shfl_xor(s, 1, 64);
            if (lane == 0 && h == 0)     // single writer: h==0 block
                t1part[(size_t)(kbase + row) * NSEG_ + seg] = s;
        }
    }
}

// ---------- kernel C1: t1 segment combine (f64) — r2 verbatim ----------------
__global__ void t1sum_kernel(const float* __restrict__ t1part, double* __restrict__ t1d) {
    int k = blockIdx.x * 256 + threadIdx.x;
    if (k < K_) {
        double s = 0.0;
        for (int j = 0; j < NSEG_; ++j) s += (double)t1part[k * NSEG_ + j];
        t1d[k] = s;
    }
}

// ---------- kernel C2: scaled_dists[b][k] — r2 verbatim ----------------------
__global__ void dist_kernel(const float* __restrict__ Spart, const double* __restrict__ t1d,
                            float* __restrict__ scaled) {
    int tid = blockIdx.x * 256 + threadIdx.x;   // B*K threads
    int b = tid >> 12;
    int k = tid & 4095;
    const float4 sp = *(const float4*)&Spart[((size_t)k * 64 + b) * NSEG_];
    double s = (double)sp.x + (double)sp.y + (double)sp.z + (double)sp.w;
    const double C = -(1.0 / 0.05) * LN2_ / (double)DIM_;   // fold ln2 + mean + (-1/T)
    scaled[(size_t)b * K_ + k] = (float)(C * (t1d[k] - s));
}

// ---------- kernel D: per-row top-8 + softmax + class scatter — r12 verbatim -
__global__ void topk_kernel(const float* __restrict__ scaled, const int* __restrict__ label,
                            float* __restrict__ out) {
    __shared__ float vals[K_];
    __shared__ float rv[256];
    __shared__ int   ri[256];
    __shared__ float topv[KNN_];
    __shared__ int   topi[KNN_];
    const int b = blockIdx.x, t = threadIdx.x;
    for (int i = t; i < K_; i += 256) vals[i] = scaled[(size_t)b * K_ + i];
    __syncthreads();
    for (int it = 0; it < KNN_; ++it) {
        float bv = -INFINITY; int bi = K_;
        for (int i = t; i < K_; i += 256) {      // ascending: first max = lowest idx (tie rule)
            float v = vals[i];
            if (v > bv) { bv = v; bi = i; }
        }
        rv[t] = bv; ri[t] = bi;
        __syncthreads();
        for (int s = 128; s > 0; s >>= 1) {
            if (t < s) {
                float v2 = rv[t + s]; int i2 = ri[t + s];
                if (v2 > rv[t] || (v2 == rv[t] && i2 < ri[t])) { rv[t] = v2; ri[t] = i2; }
            }
            __syncthreads();
        }
        if (t == 0) { topv[it] = rv[0]; topi[it] = ri[0]; vals[ri[0]] = -INFINITY; }
        __syncthreads();
    }
    if (t == 0) {
        const float m = topv[0];
        float w[KNN_], s = 0.0f;
        for (int i = 0; i < KNN_; ++i) { w[i] = expf(topv[i] - m); s += w[i]; }
        float p0 = 0.0f, p1 = 0.0f;
        for (int i = 0; i < KNN_; ++i) {
            const float ww = w[i] / s;
            if (label[topi[i]] != 0) p1 += ww; else p0 += ww;
        }
        out[b * 2 + 0] = p0;
        out[b * 2 + 1] = p1;
    }
}

// ---------- launch ------------------------------------------------------------
extern "C" void kernel_launch(void* const* d_in, const int* in_sizes, int n_in,
                              void* d_out, int out_size, void* d_ws, size_t ws_size,
                              hipStream_t stream) {
    const float* logits = (const float*)d_in[0];
    const float* A      = (const float*)d_in[1];    // queue_anchor
    const int*   label  = (const int*)d_in[2];      // jax x64-off -> int32
    float*       out    = (float*)d_out;

    char* ws = (char*)d_ws;
    float*  LT     = (float*)(ws);                               // 50688*64*4 = 12,976,128
    float*  Spart  = (float*)(ws + 12976128);                    // 4096*64*4*4 = 4,194,304
    float*  t1part = (float*)(ws + 12976128 + 4194304);          // 4096*4*4   =    65,536
    double* t1d    = (double*)(ws + 12976128 + 4194304 + 65536);              //    32,768
    float*  scaled = (float*)(ws + 12976128 + 4194304 + 65536 + 32768);       // 1,048,576
    // total ~18.3 MB

    dim3 gA(DIMP_ / 256, B_);
    log_kernel<<<gA, 256, 0, stream>>>(logits, LT);

    main_kernel<<<4096, 256, 0, stream>>>(A, LT, Spart, t1part);

    t1sum_kernel<<<K_ / 256, 256, 0, stream>>>(t1part, t1d);

    dist_kernel<<<(B_ * K_) / 256, 256, 0, stream>>>(Spart, t1d, scaled);

    topk_kernel<<<B_, 256, 0, stream>>>(scaled, label, out);
}

// Round 15
// 593.922 us; speedup vs baseline: 1.2024x; 1.2024x over previous
//
#include <hip/hip_runtime.h>
#include <cstdint>
#include <cmath>

#define B_    64
#define K_    4096
#define DIM_  50257
#define DIMP_ 50688          // 198*256, zero-padded log table (round-2 value)
#define KNN_  8
#define NSEG_ 4
#define SEGD_ 12800          // segs 0-2: 25 superblocks; seg 3: 24 (guarded tail)
#define SB_   512
#define LN2_  0.6931471805599453

typedef float f32x4 __attribute__((ext_vector_type(4)));
typedef float f32x2 __attribute__((ext_vector_type(2)));

// ---------- kernel A: LT[b][d] = log2(logits[b][d]), zero-padded (r2-exact) --
__global__ void log_kernel(const float* __restrict__ logits, float* __restrict__ LT) {
    int d = blockIdx.x * 256 + threadIdx.x;     // 0..DIMP_-1
    int b = blockIdx.y;
    float v = 0.0f;
    if (d < DIM_) v = __log2f(logits[(size_t)b * DIM_ + d]);
    LT[(size_t)b * DIMP_ + d] = v;
}

// ---------- kernel B: big pass — round-12 VERBATIM (596us, absmax 0.0) plus
// t1 ROW-SPLIT: the two h-half blocks of each (ktile,seg) used to BOTH compute
// all 8 rows' t1 chains (h==1 discarded). Now h==0 computes rows 0-3 (waves
// 0-1, block-uniform branch), h==1 rows 4-7; disjoint t1part writers. Each
// chain still computed exactly once, same op order, same xor-tree -> bit-exact.
__global__ __attribute__((amdgpu_flat_work_group_size(256, 256), amdgpu_waves_per_eu(2, 4)))
void main_kernel(
        const float* __restrict__ A, const float* __restrict__ LT,
        float* __restrict__ Spart, float* __restrict__ t1part) {
    __shared__ __align__(16) float As[2][8 * SB_];   // 2 x 16 KB
    __shared__ float T1L[8][64];                     // 2 KB

    const int t    = threadIdx.x;        // 0..255
    const int lane = t & 63;
    const int wv   = t >> 6;             // 0..3

    const int bid  = blockIdx.x;         // 0..4095
    const int xcd  = bid & 7;
    const int seg  = xcd >> 1;           // 0..3 (XCD-pinned L slice)
    const int h    = xcd & 1;            // b-half
    const int kt8  = bid >> 3;           // 0..511
    const int kbase = kt8 * 8;

    const int d0   = seg * SEGD_;
    const int dend = min(d0 + SEGD_, DIM_);

    const int srow = t >> 5;             // staging row 0..7
    const int sl2  = t & 31;             // staging col base (covers sl2 and sl2+32)
    const bool do_t1 = (h == 0) ? (srow < 4) : (srow >= 4);   // wave-uniform
    const float* Arow = A + (size_t)(kbase + srow) * DIM_;
    const float* LTb0 = LT + (size_t)(h * 32 + wv * 8) * DIMP_;

    f32x2 acc2[8][4];                    // [cc][p] packs acc[cc][2p], acc[cc][2p+1]
#pragma unroll
    for (int cc = 0; cc < 8; ++cc)
#pragma unroll
        for (int p = 0; p < 4; ++p) { acc2[cc][p][0] = 0.0f; acc2[cc][p][1] = 0.0f; }
    float t1a = 0.0f, t1b = 0.0f;        // chains for (srow, sl2), (srow, sl2+32)

    // ---- prologue: batch-load superblock d0 (always a full sb: no guards)
    float a1[8], a2[8];
#pragma unroll
    for (int j = 0; j < 8; ++j) {
        a1[j] = Arow[d0 + sl2 + j * 64];
        a2[j] = Arow[d0 + sl2 + 32 + j * 64];
    }

    int cur = 0;
    for (int ds = d0; ds < dend; ds += SB_) {
        // ---- stage writes ONLY (short pre-barrier critical path)
#pragma unroll
        for (int j = 0; j < 8; ++j) {
            As[cur][srow * SB_ + sl2 + j * 64]      = a1[j];
            As[cur][srow * SB_ + sl2 + 32 + j * 64] = a2[j];
        }
        __syncthreads();                 // the ONLY barrier per superblock

        // ---- prefetch NEXT superblock's 16 A-loads (hidden under FMA phase)
        float na1[8], na2[8];
        const int ns = ds + SB_;
        if (ns < dend) {
            if (ns + SB_ <= DIM_) {
#pragma unroll
                for (int j = 0; j < 8; ++j) {
                    na1[j] = Arow[ns + sl2 + j * 64];
                    na2[j] = Arow[ns + sl2 + 32 + j * 64];
                }
            } else {
#pragma unroll
                for (int j = 0; j < 8; ++j) {
                    const int dA = ns + sl2 + j * 64;
                    na1[j] = (dA < DIM_) ? Arow[dA] : 1.0f;   // pad 1.0
                    const int dB = dA + 32;
                    na2[j] = (dB < DIM_) ? Arow[dB] : 1.0f;
                }
            }
        }

        // ---- t1 on current regs: ONLY this block's row-half (chains r2-exact)
        if (do_t1) {
#pragma unroll
            for (int j = 0; j < 8; ++j) {
                t1a = fmaf(a1[j], __log2f(a1[j]), t1a);
                t1b = fmaf(a2[j], __log2f(a2[j]), t1b);
            }
        }

        // ---- FMA phase: packed-fp32 micro-kernel (chains r2-exact per element)
#pragma unroll
        for (int slot = 0; slot < 2; ++slot) {
            const int dl = slot * 256 + lane * 4;
            const float* LTd = LTb0 + ds + dl;
            f32x4 Lv[8];
#pragma unroll
            for (int cc = 0; cc < 8; ++cc)
                __builtin_memcpy(&Lv[cc], LTd + (size_t)cc * DIMP_, 16);
            f32x4 av[8];
#pragma unroll
            for (int r = 0; r < 8; ++r)
                av[r] = *(const f32x4*)&As[cur][r * SB_ + dl];

            f32x2 avp[4][4];             // [comp][p] = (av[2p].comp, av[2p+1].comp)
#pragma unroll
            for (int p = 0; p < 4; ++p) {
#pragma unroll
                for (int comp = 0; comp < 4; ++comp) {
                    avp[comp][p][0] = av[2 * p][comp];
                    avp[comp][p][1] = av[2 * p + 1][comp];
                }
            }
#pragma unroll
            for (int cc = 0; cc < 8; ++cc) {
#pragma unroll
                for (int comp = 0; comp < 4; ++comp) {
                    f32x2 bb;
                    bb[0] = Lv[cc][comp];
                    bb[1] = Lv[cc][comp];
#pragma unroll
                    for (int p = 0; p < 4; ++p)
                        acc2[cc][p] = __builtin_elementwise_fma(avp[comp][p], bb, acc2[cc][p]);
                }
            }
        }

        // ---- roll prefetched regs into current (register rename, no copies)
        if (ns < dend) {
#pragma unroll
            for (int j = 0; j < 8; ++j) { a1[j] = na1[j]; a2[j] = na2[j]; }
        }
        cur ^= 1;
    }

    // ---- epilogue: r2-exact xor-tree (32..1); lane cc*8+r keeps its element
    float outv = 0.0f;
#pragma unroll
    for (int cc = 0; cc < 8; ++cc)
#pragma unroll
        for (int r = 0; r < 8; ++r) {
            float v = (r & 1) ? acc2[cc][r >> 1][1] : acc2[cc][r >> 1][0];
            v += __shfl_xor(v, 32, 64);
            v += __shfl_xor(v, 16, 64);
            v += __shfl_xor(v, 8, 64);
            v += __shfl_xor(v, 4, 64);
            v += __shfl_xor(v, 2, 64);
            v += __shfl_xor(v, 1, 64);
            if (lane == cc * 8 + r) outv = v;
        }
    {
        const int rr  = lane & 7;        // k-row within tile
        const int ccx = lane >> 3;       // b within wave's 8-col group
        Spart[((size_t)(kbase + rr) * 64 + (h * 4 + wv) * 8 + ccx) * NSEG_ + seg] = outv;
    }

    // ---- t1: gather this half's chains to LDS; wave 0 trees its 4 rows
    if (do_t1) {
        T1L[srow][sl2]      = t1a;
        T1L[srow][sl2 + 32] = t1b;
    }
    __syncthreads();
    if (wv == 0) {
        const int rbase = h * 4;         // h==0: rows 0-3, h==1: rows 4-7
#pragma unroll
        for (int rr = 0; rr < 4; ++rr) {
            const int row = rbase + rr;
            float s = T1L[row][lane];
            s += __shfl_xor(s, 32, 64);
            s += __shfl_xor(s, 16, 64);
            s += __shfl_xor(s, 8, 64);
            s += __shfl_xor(s, 4, 64);
            s += __shfl_xor(s, 2, 64);
            s += __shfl_xor(s, 1, 64);
            if (lane == 0)               // disjoint writers across h halves
                t1part[(size_t)(kbase + row) * NSEG_ + seg] = s;
        }
    }
}

// ---------- kernel C1: t1 segment combine (f64) — r2 verbatim ----------------
__global__ void t1sum_kernel(const float* __restrict__ t1part, double* __restrict__ t1d) {
    int k = blockIdx.x * 256 + threadIdx.x;
    if (k < K_) {
        double s = 0.0;
        for (int j = 0; j < NSEG_; ++j) s += (double)t1part[k * NSEG_ + j];
        t1d[k] = s;
    }
}

// ---------- kernel C2: scaled_dists[b][k] — r2 verbatim ----------------------
__global__ void dist_kernel(const float* __restrict__ Spart, const double* __restrict__ t1d,
                            float* __restrict__ scaled) {
    int tid = blockIdx.x * 256 + threadIdx.x;   // B*K threads
    int b = tid >> 12;
    int k = tid & 4095;
    const float4 sp = *(const float4*)&Spart[((size_t)k * 64 + b) * NSEG_];
    double s = (double)sp.x + (double)sp.y + (double)sp.z + (double)sp.w;
    const double C = -(1.0 / 0.05) * LN2_ / (double)DIM_;   // fold ln2 + mean + (-1/T)
    scaled[(size_t)b * K_ + k] = (float)(C * (t1d[k] - s));
}

// ---------- kernel D: per-row top-8 + softmax + class scatter — r12 verbatim -
__global__ void topk_kernel(const float* __restrict__ scaled, const int* __restrict__ label,
                            float* __restrict__ out) {
    __shared__ float vals[K_];
    __shared__ float rv[256];
    __shared__ int   ri[256];
    __shared__ float topv[KNN_];
    __shared__ int   topi[KNN_];
    const int b = blockIdx.x, t = threadIdx.x;
    for (int i = t; i < K_; i += 256) vals[i] = scaled[(size_t)b * K_ + i];
    __syncthreads();
    for (int it = 0; it < KNN_; ++it) {
        float bv = -INFINITY; int bi = K_;
        for (int i = t; i < K_; i += 256) {      // ascending: first max = lowest idx (tie rule)
            float v = vals[i];
            if (v > bv) { bv = v; bi = i; }
        }
        rv[t] = bv; ri[t] = bi;
        __syncthreads();
        for (int s = 128; s > 0; s >>= 1) {
            if (t < s) {
                float v2 = rv[t + s]; int i2 = ri[t + s];
                if (v2 > rv[t] || (v2 == rv[t] && i2 < ri[t])) { rv[t] = v2; ri[t] = i2; }
            }
            __syncthreads();
        }
        if (t == 0) { topv[it] = rv[0]; topi[it] = ri[0]; vals[ri[0]] = -INFINITY; }
        __syncthreads();
    }
    if (t == 0) {
        const float m = topv[0];
        float w[KNN_], s = 0.0f;
        for (int i = 0; i < KNN_; ++i) { w[i] = expf(topv[i] - m); s += w[i]; }
        float p0 = 0.0f, p1 = 0.0f;
        for (int i = 0; i < KNN_; ++i) {
            const float ww = w[i] / s;
            if (label[topi[i]] != 0) p1 += ww; else p0 += ww;
        }
        out[b * 2 + 0] = p0;
        out[b * 2 + 1] = p1;
    }
}

// ---------- launch ------------------------------------------------------------
extern "C" void kernel_launch(void* const* d_in, const int* in_sizes, int n_in,
                              void* d_out, int out_size, void* d_ws, size_t ws_size,
                              hipStream_t stream) {
    const float* logits = (const float*)d_in[0];
    const float* A      = (const float*)d_in[1];    // queue_anchor
    const int*   label  = (const int*)d_in[2];      // jax x64-off -> int32
    float*       out    = (float*)d_out;

    char* ws = (char*)d_ws;
    float*  LT     = (float*)(ws);                               // 50688*64*4 = 12,976,128
    float*  Spart  = (float*)(ws + 12976128);                    // 4096*64*4*4 = 4,194,304
    float*  t1part = (float*)(ws + 12976128 + 4194304);          // 4096*4*4   =    65,536
    double* t1d    = (double*)(ws + 12976128 + 4194304 + 65536);              //    32,768
    float*  scaled = (float*)(ws + 12976128 + 4194304 + 65536 + 32768);       // 1,048,576
    // total ~18.3 MB

    dim3 gA(DIMP_ / 256, B_);
    log_kernel<<<gA, 256, 0, stream>>>(logits, LT);

    main_kernel<<<4096, 256, 0, stream>>>(A, LT, Spart, t1part);

    t1sum_kernel<<<K_ / 256, 256, 0, stream>>>(t1part, t1d);

    dist_kernel<<<(B_ * K_) / 256, 256, 0, stream>>>(Spart, t1d, scaled);

    topk_kernel<<<B_, 256, 0, stream>>>(scaled, label, out);
}